// Round 3
// baseline (157.402 us; speedup 1.0000x reference)
//
#include <hip/hip_runtime.h>
#include <stdint.h>

#define NQ 10
#define DIMQ 1024
#define BATCH 4096

// ------------------------------------------------------- gate coefficients ---
__global__ __launch_bounds__(64) void prep_g(const float* __restrict__ wts,
                                             float* __restrict__ Gg) {
  int g = threadIdx.x;
  if (g < 40) {
    float phi = wts[g * 3 + 0], th = wts[g * 3 + 1], om = wts[g * 3 + 2];
    float ct = cosf(0.5f * th), s = sinf(0.5f * th);
    float ap = 0.5f * (phi + om), am = 0.5f * (phi - om);
    float cp = cosf(ap), spp = sinf(ap), cm = cosf(am), sm = sinf(am);
    Gg[g * 8 + 0] = ct * cp;  Gg[g * 8 + 1] = -ct * spp;  // a
    Gg[g * 8 + 2] = -s * cm;  Gg[g * 8 + 3] = -s * sm;    // b
    Gg[g * 8 + 4] = s * cm;   Gg[g * 8 + 5] = -s * sm;    // c
    Gg[g * 8 + 6] = ct * cp;  Gg[g * 8 + 7] = ct * spp;   // d
  }
}

// Layer's 10 CNOTs composed as a GF(2)-linear index map (scatter form).
__host__ __device__ constexpr int cperm_c(int x, int r) {
  for (int q = 0; q < NQ; ++q) {
    const int c = 9 - q;
    int t = c - r; if (t < 0) t += NQ;
    x ^= ((x >> c) & 1) << t;
  }
  return x;
}

// Rotation on index bit P (P<=8). State: 8 complex amps/lane,
// idx = (h<<9)|(e<<6)|lane. P>=6: reg-bit butterfly; P<6: lane-bit shfl.
template<int P>
__device__ __forceinline__ void rot_gate(float (&sR)[8], float (&sI)[8],
                                         const float* __restrict__ G, int lane) {
  const float G0 = G[0], G1 = G[1], G2 = G[2], G3 = G[3];
  const float G4 = G[4], G5 = G[5], G6 = G[6], G7 = G[7];
  if constexpr (P >= 6) {
    constexpr int mt = 1 << (P - 6);
    #pragma unroll
    for (int e0 = 0; e0 < 8; ++e0) {
      if (e0 & mt) continue;
      const int e1 = e0 | mt;
      float r0 = sR[e0], i0 = sI[e0], r1 = sR[e1], i1 = sI[e1];
      sR[e0] = G0*r0 - G1*i0 + G2*r1 - G3*i1;
      sI[e0] = G0*i0 + G1*r0 + G2*i1 + G3*r1;
      sR[e1] = G4*r0 - G5*i0 + G6*r1 - G7*i1;
      sI[e1] = G4*i0 + G5*r0 + G6*i1 + G7*r1;
    }
  } else {
    constexpr int m = 1 << P;
    const int L = (lane >> P) & 1;
    const float aR = L ? G6 : G0, aI = L ? G7 : G1;
    const float bR = L ? G4 : G2, bI = L ? G5 : G3;
    #pragma unroll
    for (int e = 0; e < 8; ++e) {
      float oR = __shfl_xor(sR[e], m, 64);
      float oI = __shfl_xor(sI[e], m, 64);
      float rr = sR[e], ii = sI[e];
      sR[e] = aR*rr - aI*ii + bR*oR - bI*oI;
      sI[e] = aR*ii + aI*rr + bR*oI + bI*oR;
    }
  }
}

// Rotation on bit 9 (wave bit): exchange halves through the pair's LDS slice.
// Single buffer, write/BARRIER/read/BARRIER. FIRST also exchanges the norm
// partial (normalization is deferred to the epilogue).
template<bool FIRST>
__device__ __forceinline__ void wave_gate(float (&sR)[8], float (&sI)[8],
                                          const float* __restrict__ G,
                                          float2* buf, int lane, int h,
                                          float& ss) {
  float2* wp = buf + ((h << 9) | lane);
  #pragma unroll
  for (int e = 0; e < 8; ++e) wp[e << 6] = make_float2(sR[e], sI[e]);
  if (FIRST && lane == 0) buf[1024 + h] = make_float2(ss, 0.f);
  __syncthreads();
  const float2* rp = buf + (((h ^ 1) << 9) | lane);
  float pR[8], pI[8];
  #pragma unroll
  for (int e = 0; e < 8; ++e) { float2 t = rp[e << 6]; pR[e] = t.x; pI[e] = t.y; }
  if (FIRST) ss += buf[1024 + (h ^ 1)].x;
  __syncthreads();
  const float aR = h ? G[6] : G[0], aI = h ? G[7] : G[1];
  const float bR = h ? G[4] : G[2], bI = h ? G[5] : G[3];
  #pragma unroll
  for (int e = 0; e < 8; ++e) {
    float r = sR[e], i = sI[e];
    sR[e] = aR*r - aI*i + bR*pR[e] - bI*pI[e];
    sI[e] = aR*i + aI*r + bR*pI[e] + bI*pR[e];
  }
}

// CNOT layer: physical permutation via pair-shared LDS scatter (bijective
// over the 10-bit index, so both waves scatter concurrently w/o collision).
template<int R>
__device__ __forceinline__ void perm_state(float (&sR)[8], float (&sI)[8],
                                           float2* buf, int lane, int h) {
  constexpr int K0 = cperm_c(1 << 0, R), K1 = cperm_c(1 << 1, R);
  constexpr int K2 = cperm_c(1 << 2, R), K3 = cperm_c(1 << 3, R);
  constexpr int K4 = cperm_c(1 << 4, R), K5 = cperm_c(1 << 5, R);
  constexpr int C6 = cperm_c(1 << 6, R), C7 = cperm_c(1 << 7, R);
  constexpr int C8 = cperm_c(1 << 8, R), C9 = cperm_c(1 << 9, R);
  const int yl = ((lane & 1)  ? K0 : 0) ^ ((lane & 2)  ? K1 : 0) ^
                 ((lane & 4)  ? K2 : 0) ^ ((lane & 8)  ? K3 : 0) ^
                 ((lane & 16) ? K4 : 0) ^ ((lane & 32) ? K5 : 0) ^
                 (h ? C9 : 0);
  #pragma unroll
  for (int e = 0; e < 8; ++e) {
    const int y = yl ^ ((e & 1) ? C6 : 0) ^ ((e & 2) ? C7 : 0) ^ ((e & 4) ? C8 : 0);
    buf[y] = make_float2(sR[e], sI[e]);
  }
  __syncthreads();
  const float2* rp = buf + ((h << 9) | lane);
  #pragma unroll
  for (int e = 0; e < 8; ++e) { float2 t = rp[e << 6]; sR[e] = t.x; sI[e] = t.y; }
  __syncthreads();
}

template<int L>
__device__ __forceinline__ void do_layer(float (&sR)[8], float (&sI)[8],
                                         const float* __restrict__ Gg,
                                         float2* buf, int lane, int h,
                                         float& ss) {
  const float* Gl = Gg + L * 80;
  wave_gate<L == 0>(sR, sI, Gl, buf, lane, h, ss);   // q=0 -> bit 9
  rot_gate<8>(sR, sI, Gl + 8,  lane);
  rot_gate<7>(sR, sI, Gl + 16, lane);
  rot_gate<6>(sR, sI, Gl + 24, lane);
  rot_gate<5>(sR, sI, Gl + 32, lane);
  rot_gate<4>(sR, sI, Gl + 40, lane);
  rot_gate<3>(sR, sI, Gl + 48, lane);
  rot_gate<2>(sR, sI, Gl + 56, lane);
  rot_gate<1>(sR, sI, Gl + 64, lane);
  rot_gate<0>(sR, sI, Gl + 72, lane);
  if constexpr (L < 3) perm_state<L + 1>(sR, sI, buf, lane, h);
  // layer 3's permutation (r=4) is folded into the epilogue sign masks
}

// ------------------------------------------------------- fused simulation ---
// One row per 2-wave pair (128-thread block): 8192 waves = 8/SIMD = 32/CU
// (R2 post-mortem: per-SIMD VALU issue ~30% at 4 waves/SIMD, grid-limited).
// 8 KB LDS/block -> 16 blocks/CU, LDS does not cap occupancy.
__global__ __launch_bounds__(128, 8) void vqc_sim(const float* __restrict__ X,
                                                  const float* __restrict__ Gg,
                                                  const float* __restrict__ W,
                                                  const float* __restrict__ bias,
                                                  float* __restrict__ out) {
  __shared__ float2 buf[1032];       // 1024 state slots + norm-partial slots
  const int lane = threadIdx.x & 63;
  const int h = threadIdx.x >> 6;    // wave bit = index bit 9
  const int row = blockIdx.x;

  float sR[8], sI[8];

  // ---- load own half (unnormalized; norm deferred to epilogue) ----
  const float* xr = X + (size_t)row * DIMQ + (h << 9);
  float ss = 0.f;
  #pragma unroll
  for (int e = 0; e < 8; ++e) {
    sR[e] = xr[(e << 6) | lane];     // coalesced dword loads
    ss += sR[e] * sR[e];
    sI[e] = 0.f;
  }
  #pragma unroll
  for (int off = 32; off > 0; off >>= 1) ss += __shfl_xor(ss, off, 64);

  do_layer<0>(sR, sI, Gg, buf, lane, h, ss);   // exchanges ss -> row total
  do_layer<1>(sR, sI, Gg, buf, lane, h, ss);
  do_layer<2>(sR, sI, Gg, buf, lane, h, ss);
  do_layer<3>(sR, sI, Gg, buf, lane, h, ss);

  const float rn2 = 1.0f / ss;       // |amp|^2 scale (deferred normalization)

  // ---- probs -> z (layer-3 perm r=4 folded into signs) ----
  constexpr int R4 = 4;
  constexpr int K0 = cperm_c(1, R4), K1 = cperm_c(2, R4), K2 = cperm_c(4, R4);
  constexpr int K3 = cperm_c(8, R4), K4 = cperm_c(16, R4), K5 = cperm_c(32, R4);
  constexpr int C6 = cperm_c(64, R4), C7 = cperm_c(128, R4);
  constexpr int C8 = cperm_c(256, R4), C9 = cperm_c(512, R4);
  const int yl = ((lane & 1)  ? K0 : 0) ^ ((lane & 2)  ? K1 : 0) ^
                 ((lane & 4)  ? K2 : 0) ^ ((lane & 8)  ? K3 : 0) ^
                 ((lane & 16) ? K4 : 0) ^ ((lane & 32) ? K5 : 0) ^
                 (h ? C9 : 0);
  float z[10];
  #pragma unroll
  for (int q = 0; q < 10; ++q) z[q] = 0.f;
  #pragma unroll
  for (int e = 0; e < 8; ++e) {
    const int y = yl ^ ((e & 1) ? C6 : 0) ^ ((e & 2) ? C7 : 0) ^ ((e & 4) ? C8 : 0);
    const float pr = sR[e]*sR[e] + sI[e]*sI[e];
    #pragma unroll
    for (int q = 0; q < 10; ++q)
      z[q] += ((y >> (9 - q)) & 1) ? -pr : pr;
  }
  #pragma unroll
  for (int q = 0; q < 10; ++q) {
    #pragma unroll
    for (int off = 32; off > 0; off >>= 1) z[q] += __shfl_xor(z[q], off, 64);
    z[q] *= rn2;
  }

  // ---- cross-wave combine + linear head ----
  // LDS state region is dead; last event ended with a barrier.
  if (lane == 0) {
    #pragma unroll
    for (int k = 0; k < 5; ++k)
      buf[h * 8 + k] = make_float2(z[2 * k], z[2 * k + 1]);
  }
  __syncthreads();
  if (h == 0 && lane < 16) {
    float acc = bias[lane];
    #pragma unroll
    for (int k = 0; k < 5; ++k) {
      float2 a = buf[k], b = buf[8 + k];
      acc += (a.x + b.x) * W[lane * 10 + 2 * k];
      acc += (a.y + b.y) * W[lane * 10 + 2 * k + 1];
    }
    out[(size_t)row * 16 + lane] = acc;
  }
}

extern "C" void kernel_launch(void* const* d_in, const int* in_sizes, int n_in,
                              void* d_out, int out_size, void* d_ws, size_t ws_size,
                              hipStream_t stream) {
  const float* X    = (const float*)d_in[0];
  const float* wts  = (const float*)d_in[1];
  const float* W    = (const float*)d_in[2];
  const float* bias = (const float*)d_in[3];
  float* out = (float*)d_out;
  float* Gg = (float*)d_ws;   // 40 gates x 8 coeffs = 1.25 KB

  hipLaunchKernelGGL(prep_g,  dim3(1),     dim3(64),  0, stream, wts, Gg);
  hipLaunchKernelGGL(vqc_sim, dim3(BATCH), dim3(128), 0, stream, X, Gg, W, bias, out);
}

// Round 4
// 155.273 us; speedup vs baseline: 1.0137x; 1.0137x over previous
//
#include <hip/hip_runtime.h>
#include <stdint.h>

#define NQ 10
#define DIMQ 1024
#define BATCH 4096

// ------------------------------------------------------- gate coefficients ---
__global__ __launch_bounds__(64) void prep_g(const float* __restrict__ wts,
                                             float* __restrict__ Gg) {
  int g = threadIdx.x;
  if (g < 40) {
    float phi = wts[g * 3 + 0], th = wts[g * 3 + 1], om = wts[g * 3 + 2];
    float ct = cosf(0.5f * th), s = sinf(0.5f * th);
    float ap = 0.5f * (phi + om), am = 0.5f * (phi - om);
    float cp = cosf(ap), spp = sinf(ap), cm = cosf(am), sm = sinf(am);
    Gg[g * 8 + 0] = ct * cp;  Gg[g * 8 + 1] = -ct * spp;  // a
    Gg[g * 8 + 2] = -s * cm;  Gg[g * 8 + 3] = -s * sm;    // b
    Gg[g * 8 + 4] = s * cm;   Gg[g * 8 + 5] = -s * sm;    // c
    Gg[g * 8 + 6] = ct * cp;  Gg[g * 8 + 7] = ct * spp;   // d
  }
}

// Layer's 10 CNOTs composed as a GF(2)-linear index map (scatter form).
__host__ __device__ constexpr int cperm_c(int x, int r) {
  for (int q = 0; q < NQ; ++q) {
    const int c = 9 - q;
    int t = c - r; if (t < 0) t += NQ;
    x ^= ((x >> c) & 1) << t;
  }
  return x;
}

// Rotation on index bit P (P<=8). State: 8 complex amps/lane,
// idx = (h<<9)|(e<<6)|lane. P>=6: reg-bit butterfly; P<6: lane-bit shfl.
template<int P>
__device__ __forceinline__ void rot_gate(float (&sR)[8], float (&sI)[8],
                                         const float* __restrict__ G, int lane) {
  const float G0 = G[0], G1 = G[1], G2 = G[2], G3 = G[3];
  const float G4 = G[4], G5 = G[5], G6 = G[6], G7 = G[7];
  if constexpr (P >= 6) {
    constexpr int mt = 1 << (P - 6);
    #pragma unroll
    for (int e0 = 0; e0 < 8; ++e0) {
      if (e0 & mt) continue;
      const int e1 = e0 | mt;
      float r0 = sR[e0], i0 = sI[e0], r1 = sR[e1], i1 = sI[e1];
      sR[e0] = G0*r0 - G1*i0 + G2*r1 - G3*i1;
      sI[e0] = G0*i0 + G1*r0 + G2*i1 + G3*r1;
      sR[e1] = G4*r0 - G5*i0 + G6*r1 - G7*i1;
      sI[e1] = G4*i0 + G5*r0 + G6*i1 + G7*r1;
    }
  } else {
    constexpr int m = 1 << P;
    const int L = (lane >> P) & 1;
    const float aR = L ? G6 : G0, aI = L ? G7 : G1;
    const float bR = L ? G4 : G2, bI = L ? G5 : G3;
    #pragma unroll
    for (int e = 0; e < 8; ++e) {
      float oR = __shfl_xor(sR[e], m, 64);
      float oI = __shfl_xor(sI[e], m, 64);
      float rr = sR[e], ii = sI[e];
      sR[e] = aR*rr - aI*ii + bR*oR - bI*oI;
      sI[e] = aR*ii + aI*rr + bR*oI + bI*oR;
    }
  }
}

// Rotation on bit 9 (wave bit), STREAMING form (R3 post-mortem: the pR[8]/pI[8]
// transient arrays pushed peak pressure past the 64-VGPR/8-wave budget ->
// 230 MB scratch traffic). Here the partner value is consumed immediately:
// transient live set = one float2.
template<bool FIRST>
__device__ __forceinline__ void wave_gate(float (&sR)[8], float (&sI)[8],
                                          const float* __restrict__ G,
                                          float2* buf, int lane, int h,
                                          float& ss) {
  float2* wp = buf + ((h << 9) | lane);
  #pragma unroll
  for (int e = 0; e < 8; ++e) wp[e << 6] = make_float2(sR[e], sI[e]);
  if (FIRST && lane == 0) buf[1024 + h] = make_float2(ss, 0.f);
  __syncthreads();
  const float aR = h ? G[6] : G[0], aI = h ? G[7] : G[1];
  const float bR = h ? G[4] : G[2], bI = h ? G[5] : G[3];
  const float2* rp = buf + (((h ^ 1) << 9) | lane);
  #pragma unroll
  for (int e = 0; e < 8; ++e) {
    float2 t = rp[e << 6];
    float r = sR[e], i = sI[e];
    sR[e] = aR*r - aI*i + bR*t.x - bI*t.y;
    sI[e] = aR*i + aI*r + bR*t.y + bI*t.x;
  }
  if (FIRST) ss += buf[1024 + (h ^ 1)].x;
  __syncthreads();
}

// CNOT layer: physical permutation via pair-shared LDS scatter (bijective,
// both waves scatter concurrently without collision). Scatter consumes state
// directly; gather is streaming. No transient arrays.
template<int R>
__device__ __forceinline__ void perm_state(float (&sR)[8], float (&sI)[8],
                                           float2* buf, int lane, int h) {
  constexpr int K0 = cperm_c(1 << 0, R), K1 = cperm_c(1 << 1, R);
  constexpr int K2 = cperm_c(1 << 2, R), K3 = cperm_c(1 << 3, R);
  constexpr int K4 = cperm_c(1 << 4, R), K5 = cperm_c(1 << 5, R);
  constexpr int C6 = cperm_c(1 << 6, R), C7 = cperm_c(1 << 7, R);
  constexpr int C8 = cperm_c(1 << 8, R), C9 = cperm_c(1 << 9, R);
  const int yl = ((lane & 1)  ? K0 : 0) ^ ((lane & 2)  ? K1 : 0) ^
                 ((lane & 4)  ? K2 : 0) ^ ((lane & 8)  ? K3 : 0) ^
                 ((lane & 16) ? K4 : 0) ^ ((lane & 32) ? K5 : 0) ^
                 (h ? C9 : 0);
  #pragma unroll
  for (int e = 0; e < 8; ++e) {
    const int y = yl ^ ((e & 1) ? C6 : 0) ^ ((e & 2) ? C7 : 0) ^ ((e & 4) ? C8 : 0);
    buf[y] = make_float2(sR[e], sI[e]);
  }
  __syncthreads();
  const float2* rp = buf + ((h << 9) | lane);
  #pragma unroll
  for (int e = 0; e < 8; ++e) { float2 t = rp[e << 6]; sR[e] = t.x; sI[e] = t.y; }
  __syncthreads();
}

template<int L>
__device__ __forceinline__ void do_layer(float (&sR)[8], float (&sI)[8],
                                         const float* __restrict__ Gg,
                                         float2* buf, int lane, int h,
                                         float& ss) {
  const float* Gl = Gg + L * 80;
  wave_gate<L == 0>(sR, sI, Gl, buf, lane, h, ss);   // q=0 -> bit 9
  rot_gate<8>(sR, sI, Gl + 8,  lane);
  rot_gate<7>(sR, sI, Gl + 16, lane);
  rot_gate<6>(sR, sI, Gl + 24, lane);
  rot_gate<5>(sR, sI, Gl + 32, lane);
  rot_gate<4>(sR, sI, Gl + 40, lane);
  rot_gate<3>(sR, sI, Gl + 48, lane);
  rot_gate<2>(sR, sI, Gl + 56, lane);
  rot_gate<1>(sR, sI, Gl + 64, lane);
  rot_gate<0>(sR, sI, Gl + 72, lane);
  if constexpr (L < 3) perm_state<L + 1>(sR, sI, buf, lane, h);
  // layer 3's permutation (r=4) is folded into the epilogue sign masks
}

// ------------------------------------------------------- fused simulation ---
// One row per 2-wave pair: 8192 waves = 8/SIMD = 32/CU. 8.25 KB LDS/block
// -> 16 blocks/CU, LDS does not cap occupancy. Peak register demand ~40
// (16 state + streaming temps), inside the 64-VGPR/8-wave budget.
__global__ __launch_bounds__(128, 8) void vqc_sim(const float* __restrict__ X,
                                                  const float* __restrict__ Gg,
                                                  const float* __restrict__ W,
                                                  const float* __restrict__ bias,
                                                  float* __restrict__ out) {
  __shared__ float2 buf[1032];       // 1024 state slots + norm-partial slots
  const int lane = threadIdx.x & 63;
  const int h = threadIdx.x >> 6;    // wave bit = index bit 9
  const int row = blockIdx.x;

  float sR[8], sI[8];

  // ---- load own half (unnormalized; norm deferred to epilogue) ----
  const float* xr = X + (size_t)row * DIMQ + (h << 9);
  float ss = 0.f;
  #pragma unroll
  for (int e = 0; e < 8; ++e) {
    sR[e] = xr[(e << 6) | lane];     // coalesced dword loads
    ss += sR[e] * sR[e];
    sI[e] = 0.f;
  }
  #pragma unroll
  for (int off = 32; off > 0; off >>= 1) ss += __shfl_xor(ss, off, 64);

  do_layer<0>(sR, sI, Gg, buf, lane, h, ss);   // exchanges ss -> row total
  do_layer<1>(sR, sI, Gg, buf, lane, h, ss);
  do_layer<2>(sR, sI, Gg, buf, lane, h, ss);
  do_layer<3>(sR, sI, Gg, buf, lane, h, ss);

  const float rn2 = 1.0f / ss;       // |amp|^2 scale (deferred normalization)

  // ---- probs -> z (layer-3 perm r=4 folded into signs) ----
  constexpr int R4 = 4;
  constexpr int K0 = cperm_c(1, R4), K1 = cperm_c(2, R4), K2 = cperm_c(4, R4);
  constexpr int K3 = cperm_c(8, R4), K4 = cperm_c(16, R4), K5 = cperm_c(32, R4);
  constexpr int C6 = cperm_c(64, R4), C7 = cperm_c(128, R4);
  constexpr int C8 = cperm_c(256, R4), C9 = cperm_c(512, R4);
  const int yl = ((lane & 1)  ? K0 : 0) ^ ((lane & 2)  ? K1 : 0) ^
                 ((lane & 4)  ? K2 : 0) ^ ((lane & 8)  ? K3 : 0) ^
                 ((lane & 16) ? K4 : 0) ^ ((lane & 32) ? K5 : 0) ^
                 (h ? C9 : 0);
  float z[10];
  #pragma unroll
  for (int q = 0; q < 10; ++q) z[q] = 0.f;
  #pragma unroll
  for (int e = 0; e < 8; ++e) {
    const int y = yl ^ ((e & 1) ? C6 : 0) ^ ((e & 2) ? C7 : 0) ^ ((e & 4) ? C8 : 0);
    const float pr = sR[e]*sR[e] + sI[e]*sI[e];
    #pragma unroll
    for (int q = 0; q < 10; ++q)
      z[q] += ((y >> (9 - q)) & 1) ? -pr : pr;
  }
  #pragma unroll
  for (int q = 0; q < 10; ++q) {
    #pragma unroll
    for (int off = 32; off > 0; off >>= 1) z[q] += __shfl_xor(z[q], off, 64);
    z[q] *= rn2;
  }

  // ---- cross-wave combine + linear head ----
  if (lane == 0) {
    #pragma unroll
    for (int k = 0; k < 5; ++k)
      buf[h * 8 + k] = make_float2(z[2 * k], z[2 * k + 1]);
  }
  __syncthreads();
  if (h == 0 && lane < 16) {
    float acc = bias[lane];
    #pragma unroll
    for (int k = 0; k < 5; ++k) {
      float2 a = buf[k], b = buf[8 + k];
      acc += (a.x + b.x) * W[lane * 10 + 2 * k];
      acc += (a.y + b.y) * W[lane * 10 + 2 * k + 1];
    }
    out[(size_t)row * 16 + lane] = acc;
  }
}

extern "C" void kernel_launch(void* const* d_in, const int* in_sizes, int n_in,
                              void* d_out, int out_size, void* d_ws, size_t ws_size,
                              hipStream_t stream) {
  const float* X    = (const float*)d_in[0];
  const float* wts  = (const float*)d_in[1];
  const float* W    = (const float*)d_in[2];
  const float* bias = (const float*)d_in[3];
  float* out = (float*)d_out;
  float* Gg = (float*)d_ws;   // 40 gates x 8 coeffs = 1.25 KB

  hipLaunchKernelGGL(prep_g,  dim3(1),     dim3(64),  0, stream, wts, Gg);
  hipLaunchKernelGGL(vqc_sim, dim3(BATCH), dim3(128), 0, stream, X, Gg, W, bias, out);
}

// Round 5
// 134.837 us; speedup vs baseline: 1.1674x; 1.1516x over previous
//
#include <hip/hip_runtime.h>
#include <stdint.h>

#define NQ 10
#define DIMQ 1024
#define BATCH 4096

// ------------------------------------------------------- gate coefficients ---
__global__ __launch_bounds__(64) void prep_g(const float* __restrict__ wts,
                                             float* __restrict__ Gg) {
  int g = threadIdx.x;
  if (g < 40) {
    float phi = wts[g * 3 + 0], th = wts[g * 3 + 1], om = wts[g * 3 + 2];
    float ct = cosf(0.5f * th), s = sinf(0.5f * th);
    float ap = 0.5f * (phi + om), am = 0.5f * (phi - om);
    float cp = cosf(ap), spp = sinf(ap), cm = cosf(am), sm = sinf(am);
    Gg[g * 8 + 0] = ct * cp;  Gg[g * 8 + 1] = -ct * spp;  // a
    Gg[g * 8 + 2] = -s * cm;  Gg[g * 8 + 3] = -s * sm;    // b
    Gg[g * 8 + 4] = s * cm;   Gg[g * 8 + 5] = -s * sm;    // c
    Gg[g * 8 + 6] = ct * cp;  Gg[g * 8 + 7] = ct * spp;   // d
  }
}

// Layer's 10 CNOTs composed as a GF(2)-linear index map (scatter form).
__host__ __device__ constexpr int cperm_c(int x, int r) {
  for (int q = 0; q < NQ; ++q) {
    const int c = 9 - q;
    int t = c - r; if (t < 0) t += NQ;
    x ^= ((x >> c) & 1) << t;
  }
  return x;
}

// Rotation on index bit P (P<=8). State: 8 complex amps/lane,
// idx = (h<<9)|(e<<6)|lane. P>=6: reg-bit butterfly; P<6: lane-bit shfl.
template<int P>
__device__ __forceinline__ void rot_gate(float (&sR)[8], float (&sI)[8],
                                         const float* __restrict__ G, int lane) {
  const float G0 = G[0], G1 = G[1], G2 = G[2], G3 = G[3];
  const float G4 = G[4], G5 = G[5], G6 = G[6], G7 = G[7];
  if constexpr (P >= 6) {
    constexpr int mt = 1 << (P - 6);
    #pragma unroll
    for (int e0 = 0; e0 < 8; ++e0) {
      if (e0 & mt) continue;
      const int e1 = e0 | mt;
      float r0 = sR[e0], i0 = sI[e0], r1 = sR[e1], i1 = sI[e1];
      sR[e0] = G0*r0 - G1*i0 + G2*r1 - G3*i1;
      sI[e0] = G0*i0 + G1*r0 + G2*i1 + G3*r1;
      sR[e1] = G4*r0 - G5*i0 + G6*r1 - G7*i1;
      sI[e1] = G4*i0 + G5*r0 + G6*i1 + G7*r1;
    }
  } else {
    constexpr int m = 1 << P;
    const int L = (lane >> P) & 1;
    const float aR = L ? G6 : G0, aI = L ? G7 : G1;
    const float bR = L ? G4 : G2, bI = L ? G5 : G3;
    #pragma unroll
    for (int e = 0; e < 8; ++e) {
      float oR = __shfl_xor(sR[e], m, 64);
      float oI = __shfl_xor(sI[e], m, 64);
      float rr = sR[e], ii = sI[e];
      sR[e] = aR*rr - aI*ii + bR*oR - bI*oI;
      sI[e] = aR*ii + aI*rr + bR*oI + bI*oR;
    }
  }
}

// Rotation on bit 9 (wave bit), streaming form: partner value consumed
// immediately, transient live set = one float2.
template<bool FIRST>
__device__ __forceinline__ void wave_gate(float (&sR)[8], float (&sI)[8],
                                          const float* __restrict__ G,
                                          float2* buf, int lane, int h,
                                          float& ss) {
  float2* wp = buf + ((h << 9) | lane);
  #pragma unroll
  for (int e = 0; e < 8; ++e) wp[e << 6] = make_float2(sR[e], sI[e]);
  if (FIRST && lane == 0) buf[1024 + h] = make_float2(ss, 0.f);
  __syncthreads();
  const float aR = h ? G[6] : G[0], aI = h ? G[7] : G[1];
  const float bR = h ? G[4] : G[2], bI = h ? G[5] : G[3];
  const float2* rp = buf + (((h ^ 1) << 9) | lane);
  #pragma unroll
  for (int e = 0; e < 8; ++e) {
    float2 t = rp[e << 6];
    float r = sR[e], i = sI[e];
    sR[e] = aR*r - aI*i + bR*t.x - bI*t.y;
    sI[e] = aR*i + aI*r + bR*t.y + bI*t.x;
  }
  if (FIRST) ss += buf[1024 + (h ^ 1)].x;
  __syncthreads();
}

// CNOT layer: physical permutation via pair-shared LDS scatter (bijective,
// both waves scatter concurrently without collision). Streaming, no arrays.
template<int R>
__device__ __forceinline__ void perm_state(float (&sR)[8], float (&sI)[8],
                                           float2* buf, int lane, int h) {
  constexpr int K0 = cperm_c(1 << 0, R), K1 = cperm_c(1 << 1, R);
  constexpr int K2 = cperm_c(1 << 2, R), K3 = cperm_c(1 << 3, R);
  constexpr int K4 = cperm_c(1 << 4, R), K5 = cperm_c(1 << 5, R);
  constexpr int C6 = cperm_c(1 << 6, R), C7 = cperm_c(1 << 7, R);
  constexpr int C8 = cperm_c(1 << 8, R), C9 = cperm_c(1 << 9, R);
  const int yl = ((lane & 1)  ? K0 : 0) ^ ((lane & 2)  ? K1 : 0) ^
                 ((lane & 4)  ? K2 : 0) ^ ((lane & 8)  ? K3 : 0) ^
                 ((lane & 16) ? K4 : 0) ^ ((lane & 32) ? K5 : 0) ^
                 (h ? C9 : 0);
  #pragma unroll
  for (int e = 0; e < 8; ++e) {
    const int y = yl ^ ((e & 1) ? C6 : 0) ^ ((e & 2) ? C7 : 0) ^ ((e & 4) ? C8 : 0);
    buf[y] = make_float2(sR[e], sI[e]);
  }
  __syncthreads();
  const float2* rp = buf + ((h << 9) | lane);
  #pragma unroll
  for (int e = 0; e < 8; ++e) { float2 t = rp[e << 6]; sR[e] = t.x; sI[e] = t.y; }
  __syncthreads();
}

template<int L>
__device__ __forceinline__ void do_layer(float (&sR)[8], float (&sI)[8],
                                         const float* __restrict__ Gg,
                                         float2* buf, int lane, int h,
                                         float& ss) {
  const float* Gl = Gg + L * 80;
  wave_gate<L == 0>(sR, sI, Gl, buf, lane, h, ss);   // q=0 -> bit 9
  rot_gate<8>(sR, sI, Gl + 8,  lane);
  rot_gate<7>(sR, sI, Gl + 16, lane);
  rot_gate<6>(sR, sI, Gl + 24, lane);
  rot_gate<5>(sR, sI, Gl + 32, lane);
  rot_gate<4>(sR, sI, Gl + 40, lane);
  rot_gate<3>(sR, sI, Gl + 48, lane);
  rot_gate<2>(sR, sI, Gl + 56, lane);
  rot_gate<1>(sR, sI, Gl + 64, lane);
  rot_gate<0>(sR, sI, Gl + 72, lane);
  if constexpr (L < 3) perm_state<L + 1>(sR, sI, buf, lane, h);
  // layer 3's permutation (r=4) is folded into the epilogue sign masks
}

// ------------------------------------------------------- fused simulation ---
// One row per 2-wave pair: 8192 waves. R3/R4 post-mortem: hipcc's VGPR budget
// is 256/min_waves_per_EU (legacy GCN formula) -> launch_bounds(128,8) gave a
// 32-VGPR vice and 230 MB of scratch. Declare min_waves=4 (budget 64); the
// HARDWARE still schedules 8 waves/SIMD for any kernel <=64 VGPRs (pool=512).
__global__ __launch_bounds__(128, 4) void vqc_sim(const float* __restrict__ X,
                                                  const float* __restrict__ Gg,
                                                  const float* __restrict__ W,
                                                  const float* __restrict__ bias,
                                                  float* __restrict__ out) {
  __shared__ float2 buf[1032];       // 1024 state slots + norm-partial slots
  const int lane = threadIdx.x & 63;
  const int h = threadIdx.x >> 6;    // wave bit = index bit 9
  const int row = blockIdx.x;

  float sR[8], sI[8];

  // ---- load own half (unnormalized; norm deferred to epilogue) ----
  const float* xr = X + (size_t)row * DIMQ + (h << 9);
  float ss = 0.f;
  #pragma unroll
  for (int e = 0; e < 8; ++e) {
    sR[e] = xr[(e << 6) | lane];     // coalesced dword loads
    ss += sR[e] * sR[e];
    sI[e] = 0.f;
  }
  #pragma unroll
  for (int off = 32; off > 0; off >>= 1) ss += __shfl_xor(ss, off, 64);

  do_layer<0>(sR, sI, Gg, buf, lane, h, ss);   // exchanges ss -> row total
  do_layer<1>(sR, sI, Gg, buf, lane, h, ss);
  do_layer<2>(sR, sI, Gg, buf, lane, h, ss);
  do_layer<3>(sR, sI, Gg, buf, lane, h, ss);

  const float rn2 = 1.0f / ss;       // |amp|^2 scale (deferred normalization)

  // ---- probs -> z (layer-3 perm r=4 folded into signs) ----
  constexpr int R4 = 4;
  constexpr int K0 = cperm_c(1, R4), K1 = cperm_c(2, R4), K2 = cperm_c(4, R4);
  constexpr int K3 = cperm_c(8, R4), K4 = cperm_c(16, R4), K5 = cperm_c(32, R4);
  constexpr int C6 = cperm_c(64, R4), C7 = cperm_c(128, R4);
  constexpr int C8 = cperm_c(256, R4), C9 = cperm_c(512, R4);
  const int yl = ((lane & 1)  ? K0 : 0) ^ ((lane & 2)  ? K1 : 0) ^
                 ((lane & 4)  ? K2 : 0) ^ ((lane & 8)  ? K3 : 0) ^
                 ((lane & 16) ? K4 : 0) ^ ((lane & 32) ? K5 : 0) ^
                 (h ? C9 : 0);
  float z[10];
  #pragma unroll
  for (int q = 0; q < 10; ++q) z[q] = 0.f;
  #pragma unroll
  for (int e = 0; e < 8; ++e) {
    const int y = yl ^ ((e & 1) ? C6 : 0) ^ ((e & 2) ? C7 : 0) ^ ((e & 4) ? C8 : 0);
    const float pr = sR[e]*sR[e] + sI[e]*sI[e];
    #pragma unroll
    for (int q = 0; q < 10; ++q)
      z[q] += ((y >> (9 - q)) & 1) ? -pr : pr;
  }
  #pragma unroll
  for (int q = 0; q < 10; ++q) {
    #pragma unroll
    for (int off = 32; off > 0; off >>= 1) z[q] += __shfl_xor(z[q], off, 64);
    z[q] *= rn2;
  }

  // ---- cross-wave combine + linear head ----
  if (lane == 0) {
    #pragma unroll
    for (int k = 0; k < 5; ++k)
      buf[h * 8 + k] = make_float2(z[2 * k], z[2 * k + 1]);
  }
  __syncthreads();
  if (h == 0 && lane < 16) {
    float acc = bias[lane];
    #pragma unroll
    for (int k = 0; k < 5; ++k) {
      float2 a = buf[k], b = buf[8 + k];
      acc += (a.x + b.x) * W[lane * 10 + 2 * k];
      acc += (a.y + b.y) * W[lane * 10 + 2 * k + 1];
    }
    out[(size_t)row * 16 + lane] = acc;
  }
}

extern "C" void kernel_launch(void* const* d_in, const int* in_sizes, int n_in,
                              void* d_out, int out_size, void* d_ws, size_t ws_size,
                              hipStream_t stream) {
  const float* X    = (const float*)d_in[0];
  const float* wts  = (const float*)d_in[1];
  const float* W    = (const float*)d_in[2];
  const float* bias = (const float*)d_in[3];
  float* out = (float*)d_out;
  float* Gg = (float*)d_ws;   // 40 gates x 8 coeffs = 1.25 KB

  hipLaunchKernelGGL(prep_g,  dim3(1),     dim3(64),  0, stream, wts, Gg);
  hipLaunchKernelGGL(vqc_sim, dim3(BATCH), dim3(128), 0, stream, X, Gg, W, bias, out);
}

// Round 6
// 111.188 us; speedup vs baseline: 1.4156x; 1.2127x over previous
//
#include <hip/hip_runtime.h>
#include <stdint.h>

#define NQ 10
#define DIMQ 1024
#define BATCH 4096

// ------------------------------------------------------- gate coefficients ---
__global__ __launch_bounds__(64) void prep_g(const float* __restrict__ wts,
                                             float* __restrict__ Gg) {
  int g = threadIdx.x;
  if (g < 40) {
    float phi = wts[g * 3 + 0], th = wts[g * 3 + 1], om = wts[g * 3 + 2];
    float ct = cosf(0.5f * th), s = sinf(0.5f * th);
    float ap = 0.5f * (phi + om), am = 0.5f * (phi - om);
    float cp = cosf(ap), spp = sinf(ap), cm = cosf(am), sm = sinf(am);
    Gg[g * 8 + 0] = ct * cp;  Gg[g * 8 + 1] = -ct * spp;  // a
    Gg[g * 8 + 2] = -s * cm;  Gg[g * 8 + 3] = -s * sm;    // b
    Gg[g * 8 + 4] = s * cm;   Gg[g * 8 + 5] = -s * sm;    // c
    Gg[g * 8 + 6] = ct * cp;  Gg[g * 8 + 7] = ct * spp;   // d
  }
}

// Layer's 10 CNOTs composed as a GF(2)-linear index map (scatter form).
__host__ __device__ constexpr int cperm_c(int x, int r) {
  for (int q = 0; q < NQ; ++q) {
    const int c = 9 - q;
    int t = c - r; if (t < 0) t += NQ;
    x ^= ((x >> c) & 1) << t;
  }
  return x;
}

// LDS slot swizzles (fold high index bits into bank bits). Derived so every
// transpose write AND read pattern hits 64 distinct low-6 slots -> b64
// conflict-free. T2 needs its own (its read varies bits {9:6,3:2} only).
__device__ __forceinline__ int swz(int i)  { return i ^ ((i >> 4) & 0x3C); }
__device__ __forceinline__ int swzT(int i) { return i ^ ((i >> 4) & 0x3C) ^ ((i >> 6) & 3); }

// Register-bit rotation: butterfly on reg bit MT. Pure VALU, zero DS.
template<int MT>
__device__ __forceinline__ void reg_gate(float2 (&s)[16], const float* __restrict__ G) {
  const float G0 = G[0], G1 = G[1], G2 = G[2], G3 = G[3];
  const float G4 = G[4], G5 = G[5], G6 = G[6], G7 = G[7];
  #pragma unroll
  for (int e0 = 0; e0 < 16; ++e0) {
    if (e0 & MT) continue;
    const int e1 = e0 | MT;
    float2 x0 = s[e0], x1 = s[e1];
    s[e0].x = G0*x0.x - G1*x0.y + G2*x1.x - G3*x1.y;
    s[e0].y = G0*x0.y + G1*x0.x + G2*x1.y + G3*x1.x;
    s[e1].x = G4*x0.x - G5*x0.y + G6*x1.x - G7*x1.y;
    s[e1].y = G4*x0.y + G5*x0.x + G6*x1.y + G7*x1.x;
  }
}

// T1: reg = i[9:6] -> reg = i[5:2].   (thread holds amp i = e<<6 | lane)
// Intra-wave private LDS slice; same-wave DS ops are in-order -> no barrier.
__device__ __forceinline__ void t1(float2 (&s)[16], float2* __restrict__ L, int lane) {
  #pragma unroll
  for (int e = 0; e < 16; ++e)
    L[swz((e << 6) | lane)] = s[e];
  #pragma unroll
  for (int e = 0; e < 16; ++e)
    s[e] = L[swz(((lane >> 2) << 6) | (e << 2) | (lane & 3))];
}

// T2: reg = i[5:2] -> reg{[3:2]=i[5:4], [1:0]=i[1:0]}.
// (post-T1 thread holds amp i = (lane>>2)<<6 | e<<2 | (lane&3))
__device__ __forceinline__ void t2(float2 (&s)[16], float2* __restrict__ L, int lane) {
  #pragma unroll
  for (int e = 0; e < 16; ++e)
    L[swzT(((lane >> 2) << 6) | (e << 2) | (lane & 3))] = s[e];
  #pragma unroll
  for (int e = 0; e < 16; ++e)
    s[e] = L[swzT(((lane >> 2) << 6) | ((e >> 2) << 4) | ((lane & 3) << 2) | (e & 3))];
}

// CNOT permutation, composed with the layout-restore back to reg=i[9:6].
// Post-T2 mapping: thread (lane,e) holds amp
//   i = (lane>>2)<<6 | (e>>2)<<4 | (lane&3)<<2 | (e&3)
// -> lane bits {0,1}->i{2,3}, {2..5}->i{6..9}; e bits {0,1}->i{0,1}, {2,3}->i{4,5}.
template<int R>
__device__ __forceinline__ void perm(float2 (&s)[16], float2* __restrict__ L, int lane) {
  constexpr int P0 = cperm_c(1<<0,R), P1 = cperm_c(1<<1,R), P2 = cperm_c(1<<2,R),
                P3 = cperm_c(1<<3,R), P4 = cperm_c(1<<4,R), P5 = cperm_c(1<<5,R),
                P6 = cperm_c(1<<6,R), P7 = cperm_c(1<<7,R), P8 = cperm_c(1<<8,R),
                P9 = cperm_c(1<<9,R);
  const int yl = ((lane & 1)  ? P2 : 0) ^ ((lane & 2)  ? P3 : 0) ^
                 ((lane & 4)  ? P6 : 0) ^ ((lane & 8)  ? P7 : 0) ^
                 ((lane & 16) ? P8 : 0) ^ ((lane & 32) ? P9 : 0);
  #pragma unroll
  for (int e = 0; e < 16; ++e) {
    const int ye = ((e & 1) ? P0 : 0) ^ ((e & 2) ? P1 : 0) ^
                   ((e & 4) ? P4 : 0) ^ ((e & 8) ? P5 : 0);
    L[swz(yl ^ ye)] = s[e];
  }
  #pragma unroll
  for (int e = 0; e < 16; ++e)
    s[e] = L[swz((e << 6) | lane)];
}

template<int LYR>
__device__ __forceinline__ void do_layer(float2 (&s)[16], const float* __restrict__ Gg,
                                         float2* __restrict__ L, int lane) {
  const float* Gl = Gg + LYR * 80;
  reg_gate<8>(s, Gl + 0);    // q0 -> bit9 = e[3]
  reg_gate<4>(s, Gl + 8);    // q1 -> bit8
  reg_gate<2>(s, Gl + 16);   // q2 -> bit7
  reg_gate<1>(s, Gl + 24);   // q3 -> bit6
  t1(s, L, lane);
  reg_gate<8>(s, Gl + 32);   // q4 -> bit5 = e[3]
  reg_gate<4>(s, Gl + 40);   // q5 -> bit4
  reg_gate<2>(s, Gl + 48);   // q6 -> bit3
  reg_gate<1>(s, Gl + 56);   // q7 -> bit2
  t2(s, L, lane);
  reg_gate<2>(s, Gl + 64);   // q8 -> bit1 = e[1]
  reg_gate<1>(s, Gl + 72);   // q9 -> bit0 = e[0]
  if constexpr (LYR < 3) perm<LYR + 1>(s, L, lane);
  // layer 3's permutation (r=4) is folded into the epilogue sign masks
}

// ------------------------------------------------------- fused simulation ---
// One row per WAVE, 16 amps/lane, ALL rotation gates in-register (R5
// post-mortem: gates via shfl = ~1100 ds_bpermute/row on the shared per-CU
// DS pipe ~= 44 us floor; more waves can't fix a shared-pipe bound).
// Per row now: 3 transposes+perm per layer ~= 350 b64 DS, conflict-free.
// Zero __syncthreads: each wave owns a private 8 KB LDS slice.
__global__ __launch_bounds__(256, 2) void vqc_sim(const float* __restrict__ X,
                                                  const float* __restrict__ Gg,
                                                  const float* __restrict__ W,
                                                  const float* __restrict__ bias,
                                                  float* __restrict__ out) {
  __shared__ float2 lds[4][DIMQ];    // 32 KB -> 4 blocks/CU, 16 waves/CU
  const int lane = threadIdx.x & 63;
  const int w = threadIdx.x >> 6;
  const int row = blockIdx.x * 4 + w;
  float2* L = lds[w];

  float2 s[16];

  // ---- load (coalesced; norm deferred to epilogue) ----
  const float* xr = X + (size_t)row * DIMQ;
  float ss = 0.f;
  #pragma unroll
  for (int e = 0; e < 16; ++e) {
    s[e].x = xr[(e << 6) | lane];
    s[e].y = 0.f;
    ss += s[e].x * s[e].x;
  }
  #pragma unroll
  for (int off = 32; off > 0; off >>= 1) ss += __shfl_xor(ss, off, 64);

  do_layer<0>(s, Gg, L, lane);
  do_layer<1>(s, Gg, L, lane);
  do_layer<2>(s, Gg, L, lane);
  do_layer<3>(s, Gg, L, lane);

  const float rn2 = 1.0f / ss;       // probability scale (deferred norm)

  // ---- probs -> z (layer-3 perm r=4 folded into signs) ----
  // end-of-layer-3 mapping: i = (lane>>2)<<6 | (e>>2)<<4 | (lane&3)<<2 | (e&3)
  constexpr int R4 = 4;
  constexpr int Q0 = cperm_c(1<<0,R4), Q1 = cperm_c(1<<1,R4), Q2 = cperm_c(1<<2,R4),
                Q3 = cperm_c(1<<3,R4), Q4 = cperm_c(1<<4,R4), Q5 = cperm_c(1<<5,R4),
                Q6 = cperm_c(1<<6,R4), Q7 = cperm_c(1<<7,R4), Q8 = cperm_c(1<<8,R4),
                Q9 = cperm_c(1<<9,R4);
  const int yl = ((lane & 1)  ? Q2 : 0) ^ ((lane & 2)  ? Q3 : 0) ^
                 ((lane & 4)  ? Q6 : 0) ^ ((lane & 8)  ? Q7 : 0) ^
                 ((lane & 16) ? Q8 : 0) ^ ((lane & 32) ? Q9 : 0);
  float z[10];
  #pragma unroll
  for (int q = 0; q < 10; ++q) z[q] = 0.f;
  #pragma unroll
  for (int e = 0; e < 16; ++e) {
    const int y = yl ^ (((e & 1) ? Q0 : 0) ^ ((e & 2) ? Q1 : 0) ^
                        ((e & 4) ? Q4 : 0) ^ ((e & 8) ? Q5 : 0));
    const float pr = s[e].x * s[e].x + s[e].y * s[e].y;
    #pragma unroll
    for (int q = 0; q < 10; ++q)
      z[q] += ((y >> (9 - q)) & 1) ? -pr : pr;
  }
  #pragma unroll
  for (int q = 0; q < 10; ++q) {
    #pragma unroll
    for (int off = 32; off > 0; off >>= 1) z[q] += __shfl_xor(z[q], off, 64);
    z[q] *= rn2;
  }

  // ---- linear head ----
  if (lane < 16) {
    float acc = bias[lane];
    #pragma unroll
    for (int q = 0; q < 10; ++q) acc += z[q] * W[lane * 10 + q];
    out[(size_t)row * 16 + lane] = acc;
  }
}

extern "C" void kernel_launch(void* const* d_in, const int* in_sizes, int n_in,
                              void* d_out, int out_size, void* d_ws, size_t ws_size,
                              hipStream_t stream) {
  const float* X    = (const float*)d_in[0];
  const float* wts  = (const float*)d_in[1];
  const float* W    = (const float*)d_in[2];
  const float* bias = (const float*)d_in[3];
  float* out = (float*)d_out;
  float* Gg = (float*)d_ws;   // 40 gates x 8 coeffs = 1.25 KB

  hipLaunchKernelGGL(prep_g,  dim3(1),         dim3(64),  0, stream, wts, Gg);
  hipLaunchKernelGGL(vqc_sim, dim3(BATCH / 4), dim3(256), 0, stream, X, Gg, W, bias, out);
}